// Round 1
// baseline (272.304 us; speedup 1.0000x reference)
//
#include <hip/hip_runtime.h>
#include <hip/hip_bf16.h>
#include <math.h>

// Problem constants (from reference)
constexpr int   NC      = 181;        // NUM_CLASSES
constexpr int   BATCH   = 131072;
constexpr float MODC    = 6.2831853071795864769f;   // 2*pi
constexpr float HALFMOD = 3.1415926535897932385f;   // pi
constexpr float DEG2RAD = 0.017453292519943295f;    // pi/180

__device__ __forceinline__ float sq_mod_diff(float x) {
    // d = mod(x + pi, 2pi) - pi;  return d*d
    float t = x + HALFMOD;
    float m = t - floorf(t * (1.0f / MODC)) * MODC;
    float d = m - HALFMOD;
    return d * d;
}

// One wave (64 lanes) per row; each wave processes RPW consecutive rows.
// Block = 256 threads = 4 waves. Grid = BATCH / (4*RPW) blocks.
constexpr int RPW = 4;

__global__ __launch_bounds__(256) void rmspe_kernel(
    const float* __restrict__ logits,
    const int*   __restrict__ labels,
    float*       __restrict__ out)
{
    const int lane    = threadIdx.x & 63;
    const int waveBlk = threadIdx.x >> 6;
    const long long gwave = (long long)blockIdx.x * 4 + waveBlk;

    float sum = 0.0f;

    #pragma unroll
    for (int k = 0; k < RPW; ++k) {
        const long long row  = gwave * RPW + k;         // always < BATCH by grid sizing
        const size_t    base = (size_t)row * NC;

        // ---- scan 181 labels, coalesced: 3 wave-wide loads ----
        int l0 = labels[base + lane];
        int l1 = labels[base + 64 + lane];
        int l2 = (lane < NC - 128) ? labels[base + 128 + lane] : 0;

        unsigned long long m0 = __ballot(l0 != 0);
        unsigned long long m1 = __ballot(l1 != 0);
        unsigned long long m2 = __ballot(l2 != 0);

        // ---- extract the 4 set-bit positions (wave-uniform control flow) ----
        float ang[4];
        #pragma unroll
        for (int t = 0; t < 4; ++t) {
            int p;
            if (m0)      { p =       __builtin_ctzll(m0); m0 &= m0 - 1; }
            else if (m1) { p = 64  + __builtin_ctzll(m1); m1 &= m1 - 1; }
            else         { p = 128 + __builtin_ctzll(m2); m2 &= m2 - 1; }
            ang[t] = ((float)p * 1.0f - 90.0f) * DEG2RAD;
        }

        // ---- first 4 logits of the row (doa), broadcast to all lanes ----
        float v = (lane < 4) ? logits[base + lane] : 0.0f;
        float doa[4];
        doa[0] = __shfl(v, 0);
        doa[1] = __shfl(v, 1);
        doa[2] = __shfl(v, 2);
        doa[3] = __shfl(v, 3);

        // ---- 4x4 cost matrix ----
        float c[4][4];
        #pragma unroll
        for (int i = 0; i < 4; ++i)
            #pragma unroll
            for (int j = 0; j < 4; ++j)
                c[i][j] = sq_mod_diff(doa[i] - ang[j]);

        // ---- min over all 24 permutations (fully unrolled) ----
        float best = 1e30f;
        #pragma unroll
        for (int a = 0; a < 4; ++a) {
            #pragma unroll
            for (int b = 0; b < 4; ++b) {
                if (b == a) continue;
                #pragma unroll
                for (int e = 0; e < 4; ++e) {
                    if (e == a || e == b) continue;
                    const int f = 6 - a - b - e;
                    float s = c[0][a] + c[1][b] + c[2][e] + c[3][f];
                    best = fminf(best, s);
                }
            }
        }

        sum += sqrtf(best * 0.25f);
    }

    // ---- block reduction: 4 wave-uniform partial sums -> 1 atomic ----
    __shared__ float wsum[4];
    if (lane == 0) wsum[waveBlk] = sum;
    __syncthreads();
    if (threadIdx.x == 0) {
        float t = (wsum[0] + wsum[1]) + (wsum[2] + wsum[3]);
        atomicAdd(out, t * (1.0f / (float)BATCH));
    }
}

extern "C" void kernel_launch(void* const* d_in, const int* in_sizes, int n_in,
                              void* d_out, int out_size, void* d_ws, size_t ws_size,
                              hipStream_t stream) {
    const float* logits = (const float*)d_in[0];
    const int*   labels = (const int*)d_in[1];
    float*       out    = (float*)d_out;

    // d_out is poisoned (0xAA) before every launch — zero it first.
    hipMemsetAsync(out, 0, sizeof(float), stream);

    // BATCH / (4 waves * RPW rows) = 131072 / 16 = 8192 blocks
    rmspe_kernel<<<BATCH / (4 * RPW), 256, 0, stream>>>(logits, labels, out);
}

// Round 2
// 201.768 us; speedup vs baseline: 1.3496x; 1.3496x over previous
//
#include <hip/hip_runtime.h>
#include <hip/hip_bf16.h>
#include <math.h>

// Problem constants (from reference)
constexpr int   NC      = 181;        // NUM_CLASSES
constexpr int   BATCH   = 131072;
constexpr float MODC    = 6.2831853071795864769f;   // 2*pi
constexpr float HALFMOD = 3.1415926535897932385f;   // pi
constexpr float DEG2RAD = 0.017453292519943295f;    // pi/180

__device__ __forceinline__ float sq_mod_diff(float x) {
    // d = mod(x + pi, 2pi) - pi;  return d*d   (floored mod, matches jnp.mod)
    float t = x + HALFMOD;
    float m = t - floorf(t * (1.0f / MODC)) * MODC;
    float d = m - HALFMOD;
    return d * d;
}

// Each wave extracts RPW rows (ballot over coalesced label loads), then
// lanes 0..RPW-1 each compute one row's permutation-min RMSE in parallel.
constexpr int RPW = 32;   // rows per wave
constexpr int CH  = 8;    // prefetch chunk (rows of labels loaded ahead)

__global__ __launch_bounds__(256) void rmspe_kernel(
    const float* __restrict__ logits,
    const int*   __restrict__ labels,
    float*       __restrict__ out)
{
    const int lane    = threadIdx.x & 63;
    const int waveBlk = threadIdx.x >> 6;
    const int gwave   = blockIdx.x * 4 + waveBlk;
    const int rowBase = gwave * RPW;              // < BATCH by grid sizing

    // ---- preload this lane's own row doa (latency hidden behind extraction) ----
    float d0 = 0.f, d1 = 0.f, d2 = 0.f, d3 = 0.f;
    if (lane < RPW) {
        const float* lp = logits + (size_t)(rowBase + lane) * NC;
        d0 = lp[0]; d1 = lp[1]; d2 = lp[2]; d3 = lp[3];
    }

    // ---- extraction: wave scans RPW rows' labels, packs 4 indices/row ----
    int pk = 0;   // lane r (r<RPW) ends with row rowBase+r's packed indices

    for (int c = 0; c < RPW; c += CH) {
        int b0[CH], b1[CH], b2[CH];
        #pragma unroll
        for (int j = 0; j < CH; ++j) {
            const size_t b = (size_t)(rowBase + c + j) * NC;
            b0[j] = labels[b + lane];
            b1[j] = labels[b + 64 + lane];
            b2[j] = (lane < NC - 128) ? labels[b + 128 + lane] : 0;
        }
        #pragma unroll
        for (int j = 0; j < CH; ++j) {
            unsigned long long m0 = __ballot(b0[j] != 0);
            unsigned long long m1 = __ballot(b1[j] != 0);
            unsigned long long m2 = __ballot(b2[j] != 0);
            int p[4];
            #pragma unroll
            for (int t = 0; t < 4; ++t) {
                if (m0)      { p[t] =       __builtin_ctzll(m0); m0 &= m0 - 1; }
                else if (m1) { p[t] = 64  + __builtin_ctzll(m1); m1 &= m1 - 1; }
                else         { p[t] = 128 + __builtin_ctzll(m2); m2 &= m2 - 1; }
            }
            const int pack = p[0] | (p[1] << 8) | (p[2] << 16) | (p[3] << 24);
            pk = (lane == c + j) ? pack : pk;   // deposit into owning lane
        }
    }

    // ---- per-thread compute: lane r handles row rowBase+r ----
    float sum = 0.0f;
    if (lane < RPW) {
        float ang[4], doa[4] = {d0, d1, d2, d3};
        #pragma unroll
        for (int t = 0; t < 4; ++t) {
            const int p = (pk >> (8 * t)) & 0xFF;
            ang[t] = ((float)p - 90.0f) * DEG2RAD;
        }

        float cst[4][4];
        #pragma unroll
        for (int i = 0; i < 4; ++i)
            #pragma unroll
            for (int j = 0; j < 4; ++j)
                cst[i][j] = sq_mod_diff(doa[i] - ang[j]);

        // pre-sum pairs: top = c0[a]+c1[b], bot = c2[e]+c3[f]
        float best = 1e30f;
        #pragma unroll
        for (int a = 0; a < 4; ++a) {
            #pragma unroll
            for (int b = 0; b < 4; ++b) {
                if (b == a) continue;
                const float top = cst[0][a] + cst[1][b];
                #pragma unroll
                for (int e = 0; e < 4; ++e) {
                    if (e == a || e == b) continue;
                    const int f = 6 - a - b - e;
                    best = fminf(best, top + cst[2][e] + cst[3][f]);
                }
            }
        }
        sum = sqrtf(best * 0.25f);
    }

    // ---- wave reduce -> block reduce -> one atomic per block ----
    #pragma unroll
    for (int off = 32; off > 0; off >>= 1)
        sum += __shfl_down(sum, off);

    __shared__ float wsum[4];
    if (lane == 0) wsum[waveBlk] = sum;
    __syncthreads();
    if (threadIdx.x == 0) {
        float t = (wsum[0] + wsum[1]) + (wsum[2] + wsum[3]);
        atomicAdd(out, t * (1.0f / (float)BATCH));
    }
}

extern "C" void kernel_launch(void* const* d_in, const int* in_sizes, int n_in,
                              void* d_out, int out_size, void* d_ws, size_t ws_size,
                              hipStream_t stream) {
    const float* logits = (const float*)d_in[0];
    const int*   labels = (const int*)d_in[1];
    float*       out    = (float*)d_out;

    // d_out is poisoned (0xAA) before every launch — zero it first.
    hipMemsetAsync(out, 0, sizeof(float), stream);

    // BATCH / (4 waves * RPW rows) = 131072 / 128 = 1024 blocks
    rmspe_kernel<<<BATCH / (4 * RPW), 256, 0, stream>>>(logits, labels, out);
}

// Round 3
// 192.141 us; speedup vs baseline: 1.4172x; 1.0501x over previous
//
#include <hip/hip_runtime.h>
#include <hip/hip_bf16.h>
#include <math.h>

// Problem constants (from reference)
constexpr int   NC      = 181;        // NUM_CLASSES
constexpr int   BATCH   = 131072;
constexpr float MODC    = 6.2831853071795864769f;   // 2*pi
constexpr float HALFMOD = 3.1415926535897932385f;   // pi
constexpr float DEG2RAD = 0.017453292519943295f;    // pi/180

__device__ __forceinline__ float sq_mod_diff(float x) {
    // d = mod(x + pi, 2pi) - pi;  return d*d   (floored mod, matches jnp.mod)
    float t = x + HALFMOD;
    float m = t - floorf(t * (1.0f / MODC)) * MODC;
    float d = m - HALFMOD;
    return d * d;
}

// Each wave owns RPW=16 consecutive rows = 2896 contiguous ints of labels,
// loaded flat as int4 (16B-aligned since 2896*4 % 16 == 0). 11 full wave
// loads + 20-lane tail. Set-bit extraction maps flat pos -> (row, class);
// extraction order is irrelevant (perm-min is order-invariant).
constexpr int RPW    = 16;               // rows per wave
constexpr int WINTS  = RPW * NC;         // 2896 ints per wave window
constexpr int NFULL  = WINTS / 256;      // 11 full int4 wave-loads
constexpr int TAILV  = (WINTS - NFULL * 256) / 4;  // 20 tail int4 lanes
constexpr unsigned MAGIC181 = 23729102u; // ceil(2^32/181), exact for n < 25M

__global__ __launch_bounds__(256) void rmspe_kernel(
    const float* __restrict__ logits,
    const int*   __restrict__ labels,
    float*       __restrict__ out)
{
    const int lane    = threadIdx.x & 63;
    const int waveBlk = threadIdx.x >> 6;
    const int gwave   = blockIdx.x * 4 + waveBlk;
    const int rowBase = gwave * RPW;

    // ---- this lane's own row doa (issued first, latency hidden) ----
    float d0 = 0.f, d1 = 0.f, d2 = 0.f, d3 = 0.f;
    if (lane < RPW) {
        const float* lp = logits + (size_t)(rowBase + lane) * NC;
        d0 = lp[0]; d1 = lp[1]; d2 = lp[2]; d3 = lp[3];
    }

    // ---- stage 16 rows of labels flat: 12 x4 loads, all in flight ----
    const int4* p4 = (const int4*)(labels + (size_t)gwave * WINTS);
    int4 data[NFULL + 1];
    #pragma unroll
    for (int k = 0; k < NFULL; ++k)
        data[k] = p4[(size_t)k * 64 + lane];
    {
        int4 t = {0, 0, 0, 0};
        if (lane < TAILV) t = p4[(size_t)NFULL * 64 + lane];
        data[NFULL] = t;
    }

    // ---- extraction: ballot per component, pop bits, deposit to owner ----
    int pk  = 0;   // lane r (<RPW): 4 packed class indices of row rowBase+r
    int cnt = 0;

    #pragma unroll
    for (int k = 0; k < NFULL + 1; ++k) {
        const int4 v = data[k];
        unsigned long long m[4];
        m[0] = __ballot(v.x != 0);
        m[1] = __ballot(v.y != 0);
        m[2] = __ballot(v.z != 0);
        m[3] = __ballot(v.w != 0);
        #pragma unroll
        for (int c = 0; c < 4; ++c) {
            unsigned long long mm = m[c];
            while (mm) {
                const int j = __builtin_ctzll(mm);
                mm &= mm - 1;
                const unsigned g   = 256u * k + 4u * j + c;   // flat int offset
                const unsigned row = __umulhi(g, MAGIC181);   // g / 181
                const unsigned cls = g - 181u * row;          // g % 181
                const bool mine = ((unsigned)lane == row);
                const int  sh   = (cnt & 3) * 8;
                pk  = mine ? (pk | ((int)cls << sh)) : pk;
                cnt = mine ? (cnt + 1) : cnt;
            }
        }
    }

    // ---- per-thread compute: lane r handles row rowBase+r ----
    float sum = 0.0f;
    if (lane < RPW) {
        float ang[4], doa[4] = {d0, d1, d2, d3};
        #pragma unroll
        for (int t = 0; t < 4; ++t) {
            const int p = (pk >> (8 * t)) & 0xFF;
            ang[t] = ((float)p - 90.0f) * DEG2RAD;
        }

        float cst[4][4];
        #pragma unroll
        for (int i = 0; i < 4; ++i)
            #pragma unroll
            for (int j = 0; j < 4; ++j)
                cst[i][j] = sq_mod_diff(doa[i] - ang[j]);

        float best = 1e30f;
        #pragma unroll
        for (int a = 0; a < 4; ++a) {
            #pragma unroll
            for (int b = 0; b < 4; ++b) {
                if (b == a) continue;
                const float top = cst[0][a] + cst[1][b];
                #pragma unroll
                for (int e = 0; e < 4; ++e) {
                    if (e == a || e == b) continue;
                    const int f = 6 - a - b - e;
                    best = fminf(best, top + cst[2][e] + cst[3][f]);
                }
            }
        }
        sum = sqrtf(best * 0.25f);
    }

    // ---- wave reduce -> block reduce -> one atomic per block ----
    #pragma unroll
    for (int off = 32; off > 0; off >>= 1)
        sum += __shfl_down(sum, off);

    __shared__ float wsum[4];
    if (lane == 0) wsum[waveBlk] = sum;
    __syncthreads();
    if (threadIdx.x == 0) {
        float t = (wsum[0] + wsum[1]) + (wsum[2] + wsum[3]);
        atomicAdd(out, t * (1.0f / (float)BATCH));
    }
}

extern "C" void kernel_launch(void* const* d_in, const int* in_sizes, int n_in,
                              void* d_out, int out_size, void* d_ws, size_t ws_size,
                              hipStream_t stream) {
    const float* logits = (const float*)d_in[0];
    const int*   labels = (const int*)d_in[1];
    float*       out    = (float*)d_out;

    // d_out is poisoned (0xAA) before every launch — zero it first.
    hipMemsetAsync(out, 0, sizeof(float), stream);

    // BATCH / (4 waves * RPW rows) = 131072 / 64 = 2048 blocks
    rmspe_kernel<<<BATCH / (4 * RPW), 256, 0, stream>>>(logits, labels, out);
}